// Round 10
// baseline (312.579 us; speedup 1.0000x reference)
//
#include <hip/hip_runtime.h>

#define THREADS 256
#define BIGT 1024             // wide blocks for latency-bound passes
#define NBLK 256              // blocks for bin passes (private-region radix)
#define BSHIFT 8              // 256 dst-nodes per bucket
#define BSZ (1 << BSHIFT)
#define MAXB 512              // max buckets (N <= 131072)
#define TSHIFT 14             // src-tile = src >> 14 (16384 nodes = 2MB of ht per tile)
#define NT 8                  // tiles (N <= 131072)

// ---------- edge_index dtype probe: int64 high-words (values in [0,2^31)) are all 0 ----------
__global__ void detect_kernel(const unsigned int* ei_words, int* flag_int64, long long n_words) {
    __shared__ int nonzero;
    if (threadIdx.x == 0) nonzero = 0;
    __syncthreads();
    long long w = 2LL * threadIdx.x + 1;   // odd word positions = int64 high words
    if (w < n_words) {
        if (ei_words[w] != 0u) atomicOr(&nonzero, 1);
    }
    __syncthreads();
    if (threadIdx.x == 0) *flag_int64 = (nonzero == 0) ? 1 : 0;
}

// ---------- pass 1: per-block bucket histogram over dst (reads raw edge_index) ----------
__global__ __launch_bounds__(BIGT) void bin_count_kernel(
        const void* __restrict__ ei, const int* __restrict__ flag_int64,
        int* __restrict__ blockhist, int E, int NB) {
    __shared__ int h[MAXB];
    int tid = threadIdx.x;
    for (int i = tid; i < NB; i += blockDim.x) h[i] = 0;
    __syncthreads();
    int chunk = (E + gridDim.x - 1) / gridDim.x;
    int s = blockIdx.x * chunk;
    int e = min(E, s + chunk);
    if (*flag_int64) {
        const long long* p = (const long long*)ei;
        for (int i = s + tid; i < e; i += blockDim.x)
            atomicAdd(&h[(int)p[E + i] >> BSHIFT], 1);
    } else {
        const int* p = (const int*)ei;
        for (int i = s + tid; i < e; i += blockDim.x)
            atomicAdd(&h[p[E + i] >> BSHIFT], 1);
    }
    __syncthreads();
    for (int i = tid; i < NB; i += blockDim.x)
        blockhist[i * NBLK + blockIdx.x] = h[i];   // bucket-major for scan
}

// ---------- pass 2: write edges into private (bucket, block) regions; no global atomics ----------
__global__ __launch_bounds__(BIGT) void bin_write_kernel(
        const void* __restrict__ ei, const int* __restrict__ flag_int64,
        const int* __restrict__ offsets, unsigned int* __restrict__ ebuf,
        int E, int NB) {
    __shared__ int cur[MAXB];
    int tid = threadIdx.x;
    for (int i = tid; i < NB; i += blockDim.x)
        cur[i] = offsets[i * NBLK + blockIdx.x];
    __syncthreads();
    int chunk = (E + gridDim.x - 1) / gridDim.x;
    int s = blockIdx.x * chunk;
    int e = min(E, s + chunk);
    if (*flag_int64) {
        const long long* p = (const long long*)ei;
        for (int i = s + tid; i < e; i += blockDim.x) {
            int d = (int)p[E + i];
            int sr = (int)p[i];
            int pos = atomicAdd(&cur[d >> BSHIFT], 1);   // LDS cursor -> private region
            ebuf[pos] = ((unsigned int)(d & (BSZ - 1)) << 20) | (unsigned int)sr;  // src < 2^20
        }
    } else {
        const int* p = (const int*)ei;
        for (int i = s + tid; i < e; i += blockDim.x) {
            int d = p[E + i];
            int sr = p[i];
            int pos = atomicAdd(&cur[d >> BSHIFT], 1);
            ebuf[pos] = ((unsigned int)(d & (BSZ - 1)) << 20) | (unsigned int)sr;
        }
    }
}

// ---------- scan kernel 1: per-1024-chunk local exclusive scan + chunk totals ----------
__global__ void scan_blocks_kernel(const int* __restrict__ cnt, int* __restrict__ ofs,
                                   int* __restrict__ partials, int T) {
    __shared__ int sd[THREADS];
    int tid = threadIdx.x;
    int base = blockIdx.x * 1024 + tid * 4;
    int c0 = (base + 0 < T) ? cnt[base + 0] : 0;
    int c1 = (base + 1 < T) ? cnt[base + 1] : 0;
    int c2 = (base + 2 < T) ? cnt[base + 2] : 0;
    int c3 = (base + 3 < T) ? cnt[base + 3] : 0;
    int tsum = c0 + c1 + c2 + c3;
    sd[tid] = tsum;
    __syncthreads();
    for (int off = 1; off < THREADS; off <<= 1) {
        int t = (tid >= off) ? sd[tid - off] : 0;
        __syncthreads();
        sd[tid] += t;
        __syncthreads();
    }
    int excl = sd[tid] - tsum;
    if (base + 0 < T) ofs[base + 0] = excl;
    if (base + 1 < T) ofs[base + 1] = excl + c0;
    if (base + 2 < T) ofs[base + 2] = excl + c0 + c1;
    if (base + 3 < T) ofs[base + 3] = excl + c0 + c1 + c2;
    if (tid == THREADS - 1) partials[blockIdx.x] = sd[tid];
}

// ---------- scan kernel 2: each block re-scans partials in LDS, adds its prefix ----------
__global__ void scan_add2_kernel(int* __restrict__ ofs, const int* __restrict__ partials,
                                 int T, int SB) {
    __shared__ int sd[128];
    int tid = threadIdx.x;
    if (tid < 128) sd[tid] = (tid < SB) ? partials[tid] : 0;
    __syncthreads();
    for (int off = 1; off < 128; off <<= 1) {
        int t = (tid < 128 && tid >= off) ? sd[tid - off] : 0;
        __syncthreads();
        if (tid < 128) sd[tid] += t;
        __syncthreads();
    }
    int add = (blockIdx.x > 0) ? sd[blockIdx.x - 1] : 0;   // exclusive prefix of this chunk
    int base = blockIdx.x * 1024 + tid * 4;
    if (base + 0 < T) ofs[base + 0] += add;
    if (base + 1 < T) ofs[base + 1] += add;
    if (base + 2 < T) ofs[base + 2] += add;
    if (base + 3 < T) ofs[base + 3] += add;
    if (blockIdx.x == gridDim.x - 1 && tid == 0) ofs[T] = sd[SB - 1];   // grand total = E
}

// ---------- fused per-bucket: degree/rowptr/dinv + tile-ordered col placement + dense1 ----------
// one 1024-thread block per 256-node bucket; rows sorted by src-tile for agg L2-locality
__global__ __launch_bounds__(BIGT) void place_dense_kernel(
        const unsigned int* __restrict__ ebuf, const int* __restrict__ offsets,
        const float* __restrict__ x, const float* __restrict__ W1,
        int* __restrict__ rowptr, float* __restrict__ dinv, int* __restrict__ col,
        float* __restrict__ ht1, int N, int NB) {
    __shared__ int base2[BSZ * NT];    // counts -> absolute base positions (8 KB)
    __shared__ int fill2[BSZ * NT];    // cursors (8 KB)
    __shared__ int scanbuf[BSZ];
    __shared__ float dinvL[BSZ];
    __shared__ float xs[32 * 33];      // padded: group stride 33 kills bank conflicts
    int b = blockIdx.x;
    int lo = b << BSHIFT;
    int tid = threadIdx.x;
    int j0 = tid & 31;
    // W1 row j0 into registers: out_j = sum_k h[k]*W1[j][k]
    float w1r[32];
#pragma unroll
    for (int k = 0; k < 32; ++k) w1r[k] = W1[j0 * 32 + k];
    for (int i = tid; i < BSZ * NT; i += BIGT) base2[i] = 0;
    __syncthreads();
    int start = offsets[b * NBLK];
    int end   = offsets[(b + 1) * NBLK];   // b = NB-1 reads offsets[T] = E
    // pass A: per-(node, src-tile) count (ebuf region ~32KB, L2-resident)
    for (int p = start + tid; p < end; p += BIGT) {
        unsigned int v = ebuf[p];
        int dl = (v >> 20) & (BSZ - 1);
        int t  = ((v & 0xFFFFFu) >> TSHIFT) & (NT - 1);
        atomicAdd(&base2[dl * NT + t], 1);
    }
    __syncthreads();
    // per-node totals + intra-node tile prefix (registers), then cross-node scan
    int ctot = 0;
    int pre[NT];
    if (tid < BSZ) {
#pragma unroll
        for (int t = 0; t < NT; ++t) { pre[t] = ctot; ctot += base2[tid * NT + t]; }
        scanbuf[tid] = ctot;
    }
    __syncthreads();
    for (int off = 1; off < BSZ; off <<= 1) {
        int t = (tid < BSZ && tid >= off) ? scanbuf[tid - off] : 0;
        __syncthreads();
        if (tid < BSZ) scanbuf[tid] += t;
        __syncthreads();
    }
    if (tid < BSZ) {
        int excl = scanbuf[tid] - ctot;
        int nodebase = start + excl;
        int node = lo + tid;
        float dv = 1.0f / sqrtf((float)(ctot + 1));   // +1 self loop
        dinvL[tid] = dv;
        if (node < N) {
            rowptr[node] = nodebase;
            dinv[node] = dv;
            if (node == N - 1) rowptr[N] = nodebase + ctot;   // == E
        }
#pragma unroll
        for (int t = 0; t < NT; ++t) {
            base2[tid * NT + t] = nodebase + pre[t];
            fill2[tid * NT + t] = 0;
        }
    }
    __syncthreads();
    // pass B: tile-ordered place (col writes confined to this bucket's window; ebuf re-read L2-hit)
    for (int p = start + tid; p < end; p += BIGT) {
        unsigned int v = ebuf[p];
        int dl = (v >> 20) & (BSZ - 1);
        int sr = (int)(v & 0xFFFFFu);
        int idx2 = dl * NT + ((sr >> TSHIFT) & (NT - 1));
        int pos = base2[idx2] + atomicAdd(&fill2[idx2], 1);
        col[pos] = sr;
    }
    __syncthreads();
    // dense1: ht1[n] = (x[n] @ W1^T) * dinv[n]  for this bucket's 256 nodes
    for (int base0 = 0; base0 < BSZ * 32; base0 += BIGT) {
        int idx = base0 + tid;            // 0..8191
        int ln = idx >> 5;                // local node
        int node = lo + ln;
        int g = tid >> 5;                 // local group 0..31
        xs[g * 33 + j0] = (node < N) ? x[(size_t)lo * 32 + idx] : 0.f;
        __syncthreads();
        if (node < N) {
            float s = 0.f;
#pragma unroll
            for (int k = 0; k < 32; ++k) s = fmaf(xs[g * 33 + k], w1r[k], s);
            ht1[(size_t)lo * 32 + idx] = s * dinvL[ln];
        }
        __syncthreads();
    }
}

// ---------- fused agg1 + dense2: ht2 = ((relu(dinv*(gather)+b1)) @ W2^T) * dinv ----------
__global__ __launch_bounds__(THREADS) void agg_dense_kernel(
        const float* __restrict__ ht1, const int* __restrict__ rowptr,
        const int* __restrict__ col, const float* __restrict__ dinv,
        const float* __restrict__ b1, const float* __restrict__ W2,
        float* __restrict__ ht2, int N) {
    __shared__ float hr[8 * 33];  // 8 node-rows, padded stride 33
    int tid = threadIdx.x;
    int j = tid & 31;
    int g = tid >> 5;
    float w2r[32];
#pragma unroll
    for (int k = 0; k < 32; ++k) w2r[k] = W2[j * 32 + k];
    int gid = blockIdx.x * THREADS + tid;
    int n = gid >> 5;
    bool act = (n < N);
    float h1v = 0.f, dv = 0.f;
    if (act) {
        dv = dinv[n];
        float s = ht1[gid];               // self loop
        int p = rowptr[n], end = rowptr[n + 1];
        for (; p + 8 <= end; p += 8) {
            int c0 = col[p], c1 = col[p + 1], c2 = col[p + 2], c3 = col[p + 3];
            int c4 = col[p + 4], c5 = col[p + 5], c6 = col[p + 6], c7 = col[p + 7];
            float v0 = ht1[c0 * 32 + j];
            float v1 = ht1[c1 * 32 + j];
            float v2 = ht1[c2 * 32 + j];
            float v3 = ht1[c3 * 32 + j];
            float v4 = ht1[c4 * 32 + j];
            float v5 = ht1[c5 * 32 + j];
            float v6 = ht1[c6 * 32 + j];
            float v7 = ht1[c7 * 32 + j];
            s += ((v0 + v1) + (v2 + v3)) + ((v4 + v5) + (v6 + v7));
        }
        for (; p + 4 <= end; p += 4) {
            int c0 = col[p], c1 = col[p + 1], c2 = col[p + 2], c3 = col[p + 3];
            float v0 = ht1[c0 * 32 + j];
            float v1 = ht1[c1 * 32 + j];
            float v2 = ht1[c2 * 32 + j];
            float v3 = ht1[c3 * 32 + j];
            s += (v0 + v1) + (v2 + v3);
        }
        for (; p < end; ++p) s += ht1[col[p] * 32 + j];
        h1v = fmaxf(fmaf(dv, s, b1[j]), 0.f);
    }
    hr[g * 33 + j] = h1v;
    __syncthreads();
    if (act) {
        float t = 0.f;
#pragma unroll
        for (int k = 0; k < 32; ++k) t = fmaf(hr[g * 33 + k], w2r[k], t);
        ht2[gid] = t * dv;
    }
}

// ---------- final aggregate: out = relu(dinv * (self + gather) + b2) ----------
__global__ __launch_bounds__(THREADS) void agg_final_kernel(
        const float* __restrict__ ht2, const int* __restrict__ rowptr,
        const int* __restrict__ col, const float* __restrict__ dinv,
        const float* __restrict__ bias, float* __restrict__ out, int N) {
    int gid = blockIdx.x * THREADS + threadIdx.x;
    int n = gid >> 5;
    if (n >= N) return;
    int j = gid & 31;
    float s = ht2[gid];
    int p = rowptr[n], end = rowptr[n + 1];
    for (; p + 8 <= end; p += 8) {
        int c0 = col[p], c1 = col[p + 1], c2 = col[p + 2], c3 = col[p + 3];
        int c4 = col[p + 4], c5 = col[p + 5], c6 = col[p + 6], c7 = col[p + 7];
        float v0 = ht2[c0 * 32 + j];
        float v1 = ht2[c1 * 32 + j];
        float v2 = ht2[c2 * 32 + j];
        float v3 = ht2[c3 * 32 + j];
        float v4 = ht2[c4 * 32 + j];
        float v5 = ht2[c5 * 32 + j];
        float v6 = ht2[c6 * 32 + j];
        float v7 = ht2[c7 * 32 + j];
        s += ((v0 + v1) + (v2 + v3)) + ((v4 + v5) + (v6 + v7));
    }
    for (; p + 4 <= end; p += 4) {
        int c0 = col[p], c1 = col[p + 1], c2 = col[p + 2], c3 = col[p + 3];
        float v0 = ht2[c0 * 32 + j];
        float v1 = ht2[c1 * 32 + j];
        float v2 = ht2[c2 * 32 + j];
        float v3 = ht2[c3 * 32 + j];
        s += (v0 + v1) + (v2 + v3);
    }
    for (; p < end; ++p) s += ht2[col[p] * 32 + j];
    out[gid] = fmaxf(fmaf(dinv[n], s, bias[j]), 0.f);
}

extern "C" void kernel_launch(void* const* d_in, const int* in_sizes, int n_in,
                              void* d_out, int out_size, void* d_ws, size_t ws_size,
                              hipStream_t stream) {
    const float* x  = (const float*)d_in[0];
    const void*  ei = d_in[1];
    const float* W1 = (const float*)d_in[2];
    const float* b1 = (const float*)d_in[3];
    const float* W2 = (const float*)d_in[4];
    const float* b2 = (const float*)d_in[5];
    float* out = (float*)d_out;

    int N = in_sizes[0] / 32;
    long long twoE = (long long)in_sizes[1];
    int E = (int)(twoE / 2);
    int NB = (N + BSZ - 1) >> BSHIFT;          // buckets (391 for N=100000)
    int T  = NB * NBLK;                        // blockhist entries (100096)

    char* ws = (char*)d_ws;
    size_t o = 0;
    auto alloc = [&](size_t bytes) { size_t r = o; o += (bytes + 255) & ~(size_t)255; return r; };
    int*   flag      = (int*)(ws + alloc(4));
    int*   blockhist = (int*)(ws + alloc((size_t)T * 4));
    int*   offsets   = (int*)(ws + alloc((size_t)(T + 1) * 4));
    int*   rowptr    = (int*)(ws + alloc((size_t)(N + 1) * 4));
    int*   partials  = (int*)(ws + alloc(512));
    float* dinv      = (float*)(ws + alloc((size_t)N * 4));
    unsigned int* ebuf = (unsigned int*)(ws + alloc((size_t)E * 4));
    int*   col       = (int*)(ws + alloc((size_t)E * 4));
    float* ht1       = (float*)(ws + alloc((size_t)N * 32 * 4));
    float* ht2       = (float*)(ws + alloc((size_t)N * 32 * 4));

    detect_kernel<<<1, 256, 0, stream>>>((const unsigned int*)ei, flag, twoE);

    bin_count_kernel<<<NBLK, BIGT, 0, stream>>>(ei, flag, blockhist, E, NB);

    int SB = (T + 1023) / 1024;   // 98 (<=128)
    scan_blocks_kernel<<<SB, THREADS, 0, stream>>>(blockhist, offsets, partials, T);
    scan_add2_kernel<<<SB, THREADS, 0, stream>>>(offsets, partials, T, SB);

    bin_write_kernel<<<NBLK, BIGT, 0, stream>>>(ei, flag, offsets, ebuf, E, NB);
    place_dense_kernel<<<NB, BIGT, 0, stream>>>(ebuf, offsets, x, W1, rowptr, dinv, col, ht1, N, NB);

    int GB = (N * 32 + THREADS - 1) / THREADS;
    agg_dense_kernel<<<GB, THREADS, 0, stream>>>(ht1, rowptr, col, dinv, b1, W2, ht2, N);
    agg_final_kernel<<<GB, THREADS, 0, stream>>>(ht2, rowptr, col, dinv, b2, out, N);
}

// Round 11
// 307.017 us; speedup vs baseline: 1.0181x; 1.0181x over previous
//
#include <hip/hip_runtime.h>

#define THREADS 256
#define BIGT 1024             // wide blocks for latency-bound passes
#define NBLK 256              // blocks for bin passes (private-region radix)
#define BSHIFT 8              // 256 dst-nodes per bucket
#define BSZ (1 << BSHIFT)
#define MAXB 512              // max buckets (N <= 131072)

// ---------- edge_index dtype probe: int64 high-words (values in [0,2^31)) are all 0 ----------
__global__ void detect_kernel(const unsigned int* ei_words, int* flag_int64, long long n_words) {
    __shared__ int nonzero;
    if (threadIdx.x == 0) nonzero = 0;
    __syncthreads();
    long long w = 2LL * threadIdx.x + 1;   // odd word positions = int64 high words
    if (w < n_words) {
        if (ei_words[w] != 0u) atomicOr(&nonzero, 1);
    }
    __syncthreads();
    if (threadIdx.x == 0) *flag_int64 = (nonzero == 0) ? 1 : 0;
}

// ---------- pass 1: per-block bucket histogram over dst (reads raw edge_index) ----------
__global__ __launch_bounds__(BIGT) void bin_count_kernel(
        const void* __restrict__ ei, const int* __restrict__ flag_int64,
        int* __restrict__ blockhist, int E, int NB) {
    __shared__ int h[MAXB];
    int tid = threadIdx.x;
    for (int i = tid; i < NB; i += blockDim.x) h[i] = 0;
    __syncthreads();
    int chunk = (E + gridDim.x - 1) / gridDim.x;
    int s = blockIdx.x * chunk;
    int e = min(E, s + chunk);
    if (*flag_int64) {
        const long long* p = (const long long*)ei;
        for (int i = s + tid; i < e; i += blockDim.x)
            atomicAdd(&h[(int)p[E + i] >> BSHIFT], 1);
    } else {
        const int* p = (const int*)ei;
        for (int i = s + tid; i < e; i += blockDim.x)
            atomicAdd(&h[p[E + i] >> BSHIFT], 1);
    }
    __syncthreads();
    for (int i = tid; i < NB; i += blockDim.x)
        blockhist[i * NBLK + blockIdx.x] = h[i];   // bucket-major for scan
}

// ---------- pass 2: write edges into private (bucket, block) regions; no global atomics ----------
__global__ __launch_bounds__(BIGT) void bin_write_kernel(
        const void* __restrict__ ei, const int* __restrict__ flag_int64,
        const int* __restrict__ offsets, unsigned int* __restrict__ ebuf,
        int E, int NB) {
    __shared__ int cur[MAXB];
    int tid = threadIdx.x;
    for (int i = tid; i < NB; i += blockDim.x)
        cur[i] = offsets[i * NBLK + blockIdx.x];
    __syncthreads();
    int chunk = (E + gridDim.x - 1) / gridDim.x;
    int s = blockIdx.x * chunk;
    int e = min(E, s + chunk);
    if (*flag_int64) {
        const long long* p = (const long long*)ei;
        for (int i = s + tid; i < e; i += blockDim.x) {
            int d = (int)p[E + i];
            int sr = (int)p[i];
            int pos = atomicAdd(&cur[d >> BSHIFT], 1);   // LDS cursor -> private region
            ebuf[pos] = ((unsigned int)(d & (BSZ - 1)) << 20) | (unsigned int)sr;  // src < 2^20
        }
    } else {
        const int* p = (const int*)ei;
        for (int i = s + tid; i < e; i += blockDim.x) {
            int d = p[E + i];
            int sr = p[i];
            int pos = atomicAdd(&cur[d >> BSHIFT], 1);
            ebuf[pos] = ((unsigned int)(d & (BSZ - 1)) << 20) | (unsigned int)sr;
        }
    }
}

// ---------- scan kernel 1: per-1024-chunk local exclusive scan + chunk totals ----------
__global__ void scan_blocks_kernel(const int* __restrict__ cnt, int* __restrict__ ofs,
                                   int* __restrict__ partials, int T) {
    __shared__ int sd[THREADS];
    int tid = threadIdx.x;
    int base = blockIdx.x * 1024 + tid * 4;
    int c0 = (base + 0 < T) ? cnt[base + 0] : 0;
    int c1 = (base + 1 < T) ? cnt[base + 1] : 0;
    int c2 = (base + 2 < T) ? cnt[base + 2] : 0;
    int c3 = (base + 3 < T) ? cnt[base + 3] : 0;
    int tsum = c0 + c1 + c2 + c3;
    sd[tid] = tsum;
    __syncthreads();
    for (int off = 1; off < THREADS; off <<= 1) {
        int t = (tid >= off) ? sd[tid - off] : 0;
        __syncthreads();
        sd[tid] += t;
        __syncthreads();
    }
    int excl = sd[tid] - tsum;
    if (base + 0 < T) ofs[base + 0] = excl;
    if (base + 1 < T) ofs[base + 1] = excl + c0;
    if (base + 2 < T) ofs[base + 2] = excl + c0 + c1;
    if (base + 3 < T) ofs[base + 3] = excl + c0 + c1 + c2;
    if (tid == THREADS - 1) partials[blockIdx.x] = sd[tid];
}

// ---------- scan kernel 2: each block re-scans partials in LDS, adds its prefix ----------
__global__ void scan_add2_kernel(int* __restrict__ ofs, const int* __restrict__ partials,
                                 int T, int SB) {
    __shared__ int sd[128];
    int tid = threadIdx.x;
    if (tid < 128) sd[tid] = (tid < SB) ? partials[tid] : 0;
    __syncthreads();
    for (int off = 1; off < 128; off <<= 1) {
        int t = (tid < 128 && tid >= off) ? sd[tid - off] : 0;
        __syncthreads();
        if (tid < 128) sd[tid] += t;
        __syncthreads();
    }
    int add = (blockIdx.x > 0) ? sd[blockIdx.x - 1] : 0;   // exclusive prefix of this chunk
    int base = blockIdx.x * 1024 + tid * 4;
    if (base + 0 < T) ofs[base + 0] += add;
    if (base + 1 < T) ofs[base + 1] += add;
    if (base + 2 < T) ofs[base + 2] += add;
    if (base + 3 < T) ofs[base + 3] += add;
    if (blockIdx.x == gridDim.x - 1 && tid == 0) ofs[T] = sd[SB - 1];   // grand total = E
}

// ---------- fused per-bucket: degree/rowptr/dinv + col placement + dense1 ----------
// one 1024-thread block per 256-node bucket (NO tile ordering — random gather stream is faster)
__global__ __launch_bounds__(BIGT) void place_dense_kernel(
        const unsigned int* __restrict__ ebuf, const int* __restrict__ offsets,
        const float* __restrict__ x, const float* __restrict__ W1,
        int* __restrict__ rowptr, float* __restrict__ dinv, int* __restrict__ col,
        float* __restrict__ ht1, int N, int NB) {
    __shared__ int cnt[BSZ];
    __shared__ int scanbuf[BSZ];
    __shared__ int baseL[BSZ];
    __shared__ int fillL[BSZ];
    __shared__ float dinvL[BSZ];
    __shared__ float xs[32 * 33];      // padded: group stride 33 kills bank conflicts
    int b = blockIdx.x;
    int lo = b << BSHIFT;
    int tid = threadIdx.x;
    int j0 = tid & 31;
    // W1 row j0 into registers: out_j = sum_k h[k]*W1[j][k]
    float w1r[32];
#pragma unroll
    for (int k = 0; k < 32; ++k) w1r[k] = W1[j0 * 32 + k];
    if (tid < BSZ) cnt[tid] = 0;
    __syncthreads();
    int start = offsets[b * NBLK];
    int end   = offsets[(b + 1) * NBLK];   // b = NB-1 reads offsets[T] = E
    // pass A: per-node degree count (ebuf region ~32KB, L2-resident)
    for (int p = start + tid; p < end; p += BIGT)
        atomicAdd(&cnt[(ebuf[p] >> 20) & (BSZ - 1)], 1);
    __syncthreads();
    // exclusive scan of cnt (only tid<BSZ touch LDS)
    int c = (tid < BSZ) ? cnt[tid] : 0;
    if (tid < BSZ) scanbuf[tid] = c;
    __syncthreads();
    for (int off = 1; off < BSZ; off <<= 1) {
        int t = (tid < BSZ && tid >= off) ? scanbuf[tid - off] : 0;
        __syncthreads();
        if (tid < BSZ) scanbuf[tid] += t;
        __syncthreads();
    }
    if (tid < BSZ) {
        int excl = scanbuf[tid] - c;
        int node = lo + tid;
        float dv = 1.0f / sqrtf((float)(c + 1));   // +1 self loop
        dinvL[tid] = dv;
        if (node < N) {
            rowptr[node] = start + excl;
            dinv[node] = dv;
            if (node == N - 1) rowptr[N] = start + excl + c;   // == E
        }
        baseL[tid] = start + excl;
        fillL[tid] = 0;
    }
    __syncthreads();
    // pass B: place (col writes confined to this bucket's ~50KB window; ebuf re-read is L2-hit)
    for (int p = start + tid; p < end; p += BIGT) {
        unsigned int v = ebuf[p];
        int dl = (v >> 20) & (BSZ - 1);
        int pos = baseL[dl] + atomicAdd(&fillL[dl], 1);
        col[pos] = (int)(v & 0xFFFFFu);
    }
    __syncthreads();
    // dense1: ht1[n] = (x[n] @ W1^T) * dinv[n]  for this bucket's 256 nodes
    for (int base0 = 0; base0 < BSZ * 32; base0 += BIGT) {
        int idx = base0 + tid;            // 0..8191
        int ln = idx >> 5;                // local node
        int node = lo + ln;
        int g = tid >> 5;                 // local group 0..31
        xs[g * 33 + j0] = (node < N) ? x[(size_t)lo * 32 + idx] : 0.f;
        __syncthreads();
        if (node < N) {
            float s = 0.f;
#pragma unroll
            for (int k = 0; k < 32; ++k) s = fmaf(xs[g * 33 + k], w1r[k], s);
            ht1[(size_t)lo * 32 + idx] = s * dinvL[ln];
        }
        __syncthreads();
    }
}

// ---------- fused agg1 + dense2: ht2 = ((relu(dinv*(gather)+b1)) @ W2^T) * dinv ----------
__global__ __launch_bounds__(THREADS) void agg_dense_kernel(
        const float* __restrict__ ht1, const int* __restrict__ rowptr,
        const int* __restrict__ col, const float* __restrict__ dinv,
        const float* __restrict__ b1, const float* __restrict__ W2,
        float* __restrict__ ht2, int N) {
    __shared__ float hr[8 * 33];  // 8 node-rows, padded stride 33
    int tid = threadIdx.x;
    int j = tid & 31;
    int g = tid >> 5;
    float w2r[32];
#pragma unroll
    for (int k = 0; k < 32; ++k) w2r[k] = W2[j * 32 + k];
    int gid = blockIdx.x * THREADS + tid;
    int n = gid >> 5;
    bool act = (n < N);
    float h1v = 0.f, dv = 0.f;
    if (act) {
        dv = dinv[n];
        float s = ht1[gid];               // self loop
        int p = rowptr[n], end = rowptr[n + 1];
        for (; p + 8 <= end; p += 8) {
            int c0 = col[p], c1 = col[p + 1], c2 = col[p + 2], c3 = col[p + 3];
            int c4 = col[p + 4], c5 = col[p + 5], c6 = col[p + 6], c7 = col[p + 7];
            float v0 = ht1[c0 * 32 + j];
            float v1 = ht1[c1 * 32 + j];
            float v2 = ht1[c2 * 32 + j];
            float v3 = ht1[c3 * 32 + j];
            float v4 = ht1[c4 * 32 + j];
            float v5 = ht1[c5 * 32 + j];
            float v6 = ht1[c6 * 32 + j];
            float v7 = ht1[c7 * 32 + j];
            s += ((v0 + v1) + (v2 + v3)) + ((v4 + v5) + (v6 + v7));
        }
        for (; p + 4 <= end; p += 4) {
            int c0 = col[p], c1 = col[p + 1], c2 = col[p + 2], c3 = col[p + 3];
            float v0 = ht1[c0 * 32 + j];
            float v1 = ht1[c1 * 32 + j];
            float v2 = ht1[c2 * 32 + j];
            float v3 = ht1[c3 * 32 + j];
            s += (v0 + v1) + (v2 + v3);
        }
        for (; p < end; ++p) s += ht1[col[p] * 32 + j];
        h1v = fmaxf(fmaf(dv, s, b1[j]), 0.f);
    }
    hr[g * 33 + j] = h1v;
    __syncthreads();
    if (act) {
        float t = 0.f;
#pragma unroll
        for (int k = 0; k < 32; ++k) t = fmaf(hr[g * 33 + k], w2r[k], t);
        ht2[gid] = t * dv;
    }
}

// ---------- final aggregate: out = relu(dinv * (self + gather) + b2) ----------
__global__ __launch_bounds__(THREADS) void agg_final_kernel(
        const float* __restrict__ ht2, const int* __restrict__ rowptr,
        const int* __restrict__ col, const float* __restrict__ dinv,
        const float* __restrict__ bias, float* __restrict__ out, int N) {
    int gid = blockIdx.x * THREADS + threadIdx.x;
    int n = gid >> 5;
    if (n >= N) return;
    int j = gid & 31;
    float s = ht2[gid];
    int p = rowptr[n], end = rowptr[n + 1];
    for (; p + 8 <= end; p += 8) {
        int c0 = col[p], c1 = col[p + 1], c2 = col[p + 2], c3 = col[p + 3];
        int c4 = col[p + 4], c5 = col[p + 5], c6 = col[p + 6], c7 = col[p + 7];
        float v0 = ht2[c0 * 32 + j];
        float v1 = ht2[c1 * 32 + j];
        float v2 = ht2[c2 * 32 + j];
        float v3 = ht2[c3 * 32 + j];
        float v4 = ht2[c4 * 32 + j];
        float v5 = ht2[c5 * 32 + j];
        float v6 = ht2[c6 * 32 + j];
        float v7 = ht2[c7 * 32 + j];
        s += ((v0 + v1) + (v2 + v3)) + ((v4 + v5) + (v6 + v7));
    }
    for (; p + 4 <= end; p += 4) {
        int c0 = col[p], c1 = col[p + 1], c2 = col[p + 2], c3 = col[p + 3];
        float v0 = ht2[c0 * 32 + j];
        float v1 = ht2[c1 * 32 + j];
        float v2 = ht2[c2 * 32 + j];
        float v3 = ht2[c3 * 32 + j];
        s += (v0 + v1) + (v2 + v3);
    }
    for (; p < end; ++p) s += ht2[col[p] * 32 + j];
    out[gid] = fmaxf(fmaf(dinv[n], s, bias[j]), 0.f);
}

extern "C" void kernel_launch(void* const* d_in, const int* in_sizes, int n_in,
                              void* d_out, int out_size, void* d_ws, size_t ws_size,
                              hipStream_t stream) {
    const float* x  = (const float*)d_in[0];
    const void*  ei = d_in[1];
    const float* W1 = (const float*)d_in[2];
    const float* b1 = (const float*)d_in[3];
    const float* W2 = (const float*)d_in[4];
    const float* b2 = (const float*)d_in[5];
    float* out = (float*)d_out;

    int N = in_sizes[0] / 32;
    long long twoE = (long long)in_sizes[1];
    int E = (int)(twoE / 2);
    int NB = (N + BSZ - 1) >> BSHIFT;          // buckets (391 for N=100000)
    int T  = NB * NBLK;                        // blockhist entries (100096)

    char* ws = (char*)d_ws;
    size_t o = 0;
    auto alloc = [&](size_t bytes) { size_t r = o; o += (bytes + 255) & ~(size_t)255; return r; };
    int*   flag      = (int*)(ws + alloc(4));
    int*   blockhist = (int*)(ws + alloc((size_t)T * 4));
    int*   offsets   = (int*)(ws + alloc((size_t)(T + 1) * 4));
    int*   rowptr    = (int*)(ws + alloc((size_t)(N + 1) * 4));
    int*   partials  = (int*)(ws + alloc(512));
    float* dinv      = (float*)(ws + alloc((size_t)N * 4));
    unsigned int* ebuf = (unsigned int*)(ws + alloc((size_t)E * 4));
    int*   col       = (int*)(ws + alloc((size_t)E * 4));
    float* ht1       = (float*)(ws + alloc((size_t)N * 32 * 4));
    float* ht2       = (float*)(ws + alloc((size_t)N * 32 * 4));

    detect_kernel<<<1, 256, 0, stream>>>((const unsigned int*)ei, flag, twoE);

    bin_count_kernel<<<NBLK, BIGT, 0, stream>>>(ei, flag, blockhist, E, NB);

    int SB = (T + 1023) / 1024;   // 98 (<=128)
    scan_blocks_kernel<<<SB, THREADS, 0, stream>>>(blockhist, offsets, partials, T);
    scan_add2_kernel<<<SB, THREADS, 0, stream>>>(offsets, partials, T, SB);

    bin_write_kernel<<<NBLK, BIGT, 0, stream>>>(ei, flag, offsets, ebuf, E, NB);
    place_dense_kernel<<<NB, BIGT, 0, stream>>>(ebuf, offsets, x, W1, rowptr, dinv, col, ht1, N, NB);

    int GB = (N * 32 + THREADS - 1) / THREADS;
    agg_dense_kernel<<<GB, THREADS, 0, stream>>>(ht1, rowptr, col, dinv, b1, W2, ht2, N);
    agg_final_kernel<<<GB, THREADS, 0, stream>>>(ht2, rowptr, col, dinv, b2, out, N);
}

// Round 12
// 291.145 us; speedup vs baseline: 1.0736x; 1.0545x over previous
//
#include <hip/hip_runtime.h>

#define THREADS 256
#define BIGT 1024             // wide blocks for latency-bound passes
#define NBLK 256              // blocks for bin passes (private-region radix)
#define BSHIFT 8              // 256 dst-nodes per bucket
#define BSZ (1 << BSHIFT)
#define MAXB 512              // max buckets (N <= 131072)

// ---------- edge_index dtype probe: int64 high-words (values in [0,2^31)) are all 0 ----------
__global__ void detect_kernel(const unsigned int* ei_words, int* flag_int64, long long n_words) {
    __shared__ int nonzero;
    if (threadIdx.x == 0) nonzero = 0;
    __syncthreads();
    long long w = 2LL * threadIdx.x + 1;   // odd word positions = int64 high words
    if (w < n_words) {
        if (ei_words[w] != 0u) atomicOr(&nonzero, 1);
    }
    __syncthreads();
    if (threadIdx.x == 0) *flag_int64 = (nonzero == 0) ? 1 : 0;
}

// ---------- pass 1: per-block bucket histogram over dst (reads raw edge_index) ----------
__global__ __launch_bounds__(BIGT) void bin_count_kernel(
        const void* __restrict__ ei, const int* __restrict__ flag_int64,
        int* __restrict__ blockhist, int E, int NB) {
    __shared__ int h[MAXB];
    int tid = threadIdx.x;
    for (int i = tid; i < NB; i += blockDim.x) h[i] = 0;
    __syncthreads();
    int chunk = (E + gridDim.x - 1) / gridDim.x;
    int s = blockIdx.x * chunk;
    int e = min(E, s + chunk);
    if (*flag_int64) {
        const long long* p = (const long long*)ei;
        for (int i = s + tid; i < e; i += blockDim.x)
            atomicAdd(&h[(int)p[E + i] >> BSHIFT], 1);
    } else {
        const int* p = (const int*)ei;
        for (int i = s + tid; i < e; i += blockDim.x)
            atomicAdd(&h[p[E + i] >> BSHIFT], 1);
    }
    __syncthreads();
    for (int i = tid; i < NB; i += blockDim.x)
        blockhist[i * NBLK + blockIdx.x] = h[i];   // bucket-major for scan
}

// ---------- pass 2: write edges into private (bucket, block) regions; no global atomics ----------
__global__ __launch_bounds__(BIGT) void bin_write_kernel(
        const void* __restrict__ ei, const int* __restrict__ flag_int64,
        const int* __restrict__ offsets, unsigned int* __restrict__ ebuf,
        int E, int NB) {
    __shared__ int cur[MAXB];
    int tid = threadIdx.x;
    for (int i = tid; i < NB; i += blockDim.x)
        cur[i] = offsets[i * NBLK + blockIdx.x];
    __syncthreads();
    int chunk = (E + gridDim.x - 1) / gridDim.x;
    int s = blockIdx.x * chunk;
    int e = min(E, s + chunk);
    if (*flag_int64) {
        const long long* p = (const long long*)ei;
        for (int i = s + tid; i < e; i += blockDim.x) {
            int d = (int)p[E + i];
            int sr = (int)p[i];
            int pos = atomicAdd(&cur[d >> BSHIFT], 1);   // LDS cursor -> private region
            ebuf[pos] = ((unsigned int)(d & (BSZ - 1)) << 20) | (unsigned int)sr;  // src < 2^20
        }
    } else {
        const int* p = (const int*)ei;
        for (int i = s + tid; i < e; i += blockDim.x) {
            int d = p[E + i];
            int sr = p[i];
            int pos = atomicAdd(&cur[d >> BSHIFT], 1);
            ebuf[pos] = ((unsigned int)(d & (BSZ - 1)) << 20) | (unsigned int)sr;
        }
    }
}

// ---------- scan kernel 1: per-1024-chunk local exclusive scan + chunk totals ----------
__global__ void scan_blocks_kernel(const int* __restrict__ cnt, int* __restrict__ ofs,
                                   int* __restrict__ partials, int T) {
    __shared__ int sd[THREADS];
    int tid = threadIdx.x;
    int base = blockIdx.x * 1024 + tid * 4;
    int c0 = (base + 0 < T) ? cnt[base + 0] : 0;
    int c1 = (base + 1 < T) ? cnt[base + 1] : 0;
    int c2 = (base + 2 < T) ? cnt[base + 2] : 0;
    int c3 = (base + 3 < T) ? cnt[base + 3] : 0;
    int tsum = c0 + c1 + c2 + c3;
    sd[tid] = tsum;
    __syncthreads();
    for (int off = 1; off < THREADS; off <<= 1) {
        int t = (tid >= off) ? sd[tid - off] : 0;
        __syncthreads();
        sd[tid] += t;
        __syncthreads();
    }
    int excl = sd[tid] - tsum;
    if (base + 0 < T) ofs[base + 0] = excl;
    if (base + 1 < T) ofs[base + 1] = excl + c0;
    if (base + 2 < T) ofs[base + 2] = excl + c0 + c1;
    if (base + 3 < T) ofs[base + 3] = excl + c0 + c1 + c2;
    if (tid == THREADS - 1) partials[blockIdx.x] = sd[tid];
}

// ---------- scan kernel 2: each block re-scans partials in LDS, adds its prefix ----------
__global__ void scan_add2_kernel(int* __restrict__ ofs, const int* __restrict__ partials,
                                 int T, int SB) {
    __shared__ int sd[128];
    int tid = threadIdx.x;
    if (tid < 128) sd[tid] = (tid < SB) ? partials[tid] : 0;
    __syncthreads();
    for (int off = 1; off < 128; off <<= 1) {
        int t = (tid < 128 && tid >= off) ? sd[tid - off] : 0;
        __syncthreads();
        if (tid < 128) sd[tid] += t;
        __syncthreads();
    }
    int add = (blockIdx.x > 0) ? sd[blockIdx.x - 1] : 0;   // exclusive prefix of this chunk
    int base = blockIdx.x * 1024 + tid * 4;
    if (base + 0 < T) ofs[base + 0] += add;
    if (base + 1 < T) ofs[base + 1] += add;
    if (base + 2 < T) ofs[base + 2] += add;
    if (base + 3 < T) ofs[base + 3] += add;
    if (blockIdx.x == gridDim.x - 1 && tid == 0) ofs[T] = sd[SB - 1];   // grand total = E
}

// ---------- fused per-bucket: degree/rowptr/dinv + col placement + dense1 ----------
// one 1024-thread block per 256-node bucket (R9 form: Wt in LDS, no registers held across loops)
__global__ __launch_bounds__(BIGT) void place_dense_kernel(
        const unsigned int* __restrict__ ebuf, const int* __restrict__ offsets,
        const float* __restrict__ x, const float* __restrict__ W1,
        int* __restrict__ rowptr, float* __restrict__ dinv, int* __restrict__ col,
        float* __restrict__ ht1, int N, int NB) {
    __shared__ int cnt[BSZ];
    __shared__ int scanbuf[BSZ];
    __shared__ int baseL[BSZ];
    __shared__ int fillL[BSZ];
    __shared__ float dinvL[BSZ];
    __shared__ float Wt[1024];    // Wt[k*32+j] = W1[j*32+k]
    __shared__ float xs[BIGT];
    int b = blockIdx.x;
    int lo = b << BSHIFT;
    int tid = threadIdx.x;
    if (tid < BSZ) cnt[tid] = 0;
    Wt[(tid & 31) * 32 + (tid >> 5)] = W1[tid];   // BIGT == 1024 covers all
    __syncthreads();
    int start = offsets[b * NBLK];
    int end   = offsets[(b + 1) * NBLK];   // b = NB-1 reads offsets[T] = E
    // pass A: per-node degree count (ebuf region ~32KB, L2-resident)
    for (int p = start + tid; p < end; p += BIGT)
        atomicAdd(&cnt[(ebuf[p] >> 20) & (BSZ - 1)], 1);
    __syncthreads();
    // exclusive scan of cnt (only tid<BSZ touch LDS)
    int c = (tid < BSZ) ? cnt[tid] : 0;
    if (tid < BSZ) scanbuf[tid] = c;
    __syncthreads();
    for (int off = 1; off < BSZ; off <<= 1) {
        int t = (tid < BSZ && tid >= off) ? scanbuf[tid - off] : 0;
        __syncthreads();
        if (tid < BSZ) scanbuf[tid] += t;
        __syncthreads();
    }
    if (tid < BSZ) {
        int excl = scanbuf[tid] - c;
        int node = lo + tid;
        float dv = 1.0f / sqrtf((float)(c + 1));   // +1 self loop
        dinvL[tid] = dv;
        if (node < N) {
            rowptr[node] = start + excl;
            dinv[node] = dv;
            if (node == N - 1) rowptr[N] = start + excl + c;   // == E
        }
        baseL[tid] = start + excl;
        fillL[tid] = 0;
    }
    __syncthreads();
    // pass B: place (col writes confined to this bucket's ~50KB window; ebuf re-read is L2-hit)
    for (int p = start + tid; p < end; p += BIGT) {
        unsigned int v = ebuf[p];
        int dl = (v >> 20) & (BSZ - 1);
        int pos = baseL[dl] + atomicAdd(&fillL[dl], 1);
        col[pos] = (int)(v & 0xFFFFFu);
    }
    __syncthreads();
    // dense1: ht1[n] = (x[n] @ W1^T) * dinv[n]  for this bucket's 256 nodes
    for (int base0 = 0; base0 < BSZ * 32; base0 += BIGT) {
        int idx = base0 + tid;            // 0..8191
        int ln = idx >> 5;                // local node
        int node = lo + ln;
        xs[tid] = (node < N) ? x[(size_t)lo * 32 + idx] : 0.f;
        __syncthreads();
        if (node < N) {
            int j = idx & 31;
            const float* xr = xs + ((tid >> 5) << 5);
            float s = 0.f;
#pragma unroll
            for (int k = 0; k < 32; ++k) s = fmaf(xr[k], Wt[k * 32 + j], s);
            ht1[(size_t)node * 32 + j] = s * dinvL[ln];
        }
        __syncthreads();
    }
}

// ---------- fused agg1 + dense2: ht2 = ((relu(dinv*(gather)+b1)) @ W2^T) * dinv ----------
// R9 form: Wt in LDS (keeps gather-loop VGPR low -> full MLP); NT col loads (no reuse stream)
__global__ __launch_bounds__(THREADS) void agg_dense_kernel(
        const float* __restrict__ ht1, const int* __restrict__ rowptr,
        const int* __restrict__ col, const float* __restrict__ dinv,
        const float* __restrict__ b1, const float* __restrict__ W2,
        float* __restrict__ ht2, int N) {
    __shared__ float Wt[1024];    // Wt[k*32+j] = W2[j*32+k]
    __shared__ float hr[THREADS]; // 8 node-rows of h1
    int tid = threadIdx.x;
    for (int idx = tid; idx < 1024; idx += THREADS)
        Wt[(idx & 31) * 32 + (idx >> 5)] = W2[idx];
    int gid = blockIdx.x * THREADS + tid;
    int n = gid >> 5;
    int j = gid & 31;
    bool act = (n < N);
    float h1v = 0.f, dv = 0.f;
    if (act) {
        dv = dinv[n];
        float s = ht1[gid];               // self loop
        int p = rowptr[n], end = rowptr[n + 1];
        for (; p + 8 <= end; p += 8) {
            int c0 = __builtin_nontemporal_load(col + p);
            int c1 = __builtin_nontemporal_load(col + p + 1);
            int c2 = __builtin_nontemporal_load(col + p + 2);
            int c3 = __builtin_nontemporal_load(col + p + 3);
            int c4 = __builtin_nontemporal_load(col + p + 4);
            int c5 = __builtin_nontemporal_load(col + p + 5);
            int c6 = __builtin_nontemporal_load(col + p + 6);
            int c7 = __builtin_nontemporal_load(col + p + 7);
            float v0 = ht1[c0 * 32 + j];
            float v1 = ht1[c1 * 32 + j];
            float v2 = ht1[c2 * 32 + j];
            float v3 = ht1[c3 * 32 + j];
            float v4 = ht1[c4 * 32 + j];
            float v5 = ht1[c5 * 32 + j];
            float v6 = ht1[c6 * 32 + j];
            float v7 = ht1[c7 * 32 + j];
            s += ((v0 + v1) + (v2 + v3)) + ((v4 + v5) + (v6 + v7));
        }
        for (; p + 4 <= end; p += 4) {
            int c0 = __builtin_nontemporal_load(col + p);
            int c1 = __builtin_nontemporal_load(col + p + 1);
            int c2 = __builtin_nontemporal_load(col + p + 2);
            int c3 = __builtin_nontemporal_load(col + p + 3);
            float v0 = ht1[c0 * 32 + j];
            float v1 = ht1[c1 * 32 + j];
            float v2 = ht1[c2 * 32 + j];
            float v3 = ht1[c3 * 32 + j];
            s += (v0 + v1) + (v2 + v3);
        }
        for (; p < end; ++p) s += ht1[__builtin_nontemporal_load(col + p) * 32 + j];
        h1v = fmaxf(fmaf(dv, s, b1[j]), 0.f);
    }
    hr[tid] = h1v;
    __syncthreads();                       // also covers Wt load
    if (act) {
        const float* hrow = hr + ((tid >> 5) << 5);
        float t = 0.f;
#pragma unroll
        for (int k = 0; k < 32; ++k) t = fmaf(hrow[k], Wt[k * 32 + j], t);
        ht2[gid] = t * dv;
    }
}

// ---------- final aggregate: out = relu(dinv * (self + gather) + b2) ----------
__global__ __launch_bounds__(THREADS) void agg_final_kernel(
        const float* __restrict__ ht2, const int* __restrict__ rowptr,
        const int* __restrict__ col, const float* __restrict__ dinv,
        const float* __restrict__ bias, float* __restrict__ out, int N) {
    int gid = blockIdx.x * THREADS + threadIdx.x;
    int n = gid >> 5;
    if (n >= N) return;
    int j = gid & 31;
    float s = ht2[gid];
    int p = rowptr[n], end = rowptr[n + 1];
    for (; p + 8 <= end; p += 8) {
        int c0 = __builtin_nontemporal_load(col + p);
        int c1 = __builtin_nontemporal_load(col + p + 1);
        int c2 = __builtin_nontemporal_load(col + p + 2);
        int c3 = __builtin_nontemporal_load(col + p + 3);
        int c4 = __builtin_nontemporal_load(col + p + 4);
        int c5 = __builtin_nontemporal_load(col + p + 5);
        int c6 = __builtin_nontemporal_load(col + p + 6);
        int c7 = __builtin_nontemporal_load(col + p + 7);
        float v0 = ht2[c0 * 32 + j];
        float v1 = ht2[c1 * 32 + j];
        float v2 = ht2[c2 * 32 + j];
        float v3 = ht2[c3 * 32 + j];
        float v4 = ht2[c4 * 32 + j];
        float v5 = ht2[c5 * 32 + j];
        float v6 = ht2[c6 * 32 + j];
        float v7 = ht2[c7 * 32 + j];
        s += ((v0 + v1) + (v2 + v3)) + ((v4 + v5) + (v6 + v7));
    }
    for (; p + 4 <= end; p += 4) {
        int c0 = __builtin_nontemporal_load(col + p);
        int c1 = __builtin_nontemporal_load(col + p + 1);
        int c2 = __builtin_nontemporal_load(col + p + 2);
        int c3 = __builtin_nontemporal_load(col + p + 3);
        float v0 = ht2[c0 * 32 + j];
        float v1 = ht2[c1 * 32 + j];
        float v2 = ht2[c2 * 32 + j];
        float v3 = ht2[c3 * 32 + j];
        s += (v0 + v1) + (v2 + v3);
    }
    for (; p < end; ++p) s += ht2[__builtin_nontemporal_load(col + p) * 32 + j];
    float r = fmaxf(fmaf(dinv[n], s, bias[j]), 0.f);
    __builtin_nontemporal_store(r, out + gid);
}

extern "C" void kernel_launch(void* const* d_in, const int* in_sizes, int n_in,
                              void* d_out, int out_size, void* d_ws, size_t ws_size,
                              hipStream_t stream) {
    const float* x  = (const float*)d_in[0];
    const void*  ei = d_in[1];
    const float* W1 = (const float*)d_in[2];
    const float* b1 = (const float*)d_in[3];
    const float* W2 = (const float*)d_in[4];
    const float* b2 = (const float*)d_in[5];
    float* out = (float*)d_out;

    int N = in_sizes[0] / 32;
    long long twoE = (long long)in_sizes[1];
    int E = (int)(twoE / 2);
    int NB = (N + BSZ - 1) >> BSHIFT;          // buckets (391 for N=100000)
    int T  = NB * NBLK;                        // blockhist entries (100096)

    char* ws = (char*)d_ws;
    size_t o = 0;
    auto alloc = [&](size_t bytes) { size_t r = o; o += (bytes + 255) & ~(size_t)255; return r; };
    int*   flag      = (int*)(ws + alloc(4));
    int*   blockhist = (int*)(ws + alloc((size_t)T * 4));
    int*   offsets   = (int*)(ws + alloc((size_t)(T + 1) * 4));
    int*   rowptr    = (int*)(ws + alloc((size_t)(N + 1) * 4));
    int*   partials  = (int*)(ws + alloc(512));
    float* dinv      = (float*)(ws + alloc((size_t)N * 4));
    unsigned int* ebuf = (unsigned int*)(ws + alloc((size_t)E * 4));
    int*   col       = (int*)(ws + alloc((size_t)E * 4));
    float* ht1       = (float*)(ws + alloc((size_t)N * 32 * 4));
    float* ht2       = (float*)(ws + alloc((size_t)N * 32 * 4));

    detect_kernel<<<1, 256, 0, stream>>>((const unsigned int*)ei, flag, twoE);

    bin_count_kernel<<<NBLK, BIGT, 0, stream>>>(ei, flag, blockhist, E, NB);

    int SB = (T + 1023) / 1024;   // 98 (<=128)
    scan_blocks_kernel<<<SB, THREADS, 0, stream>>>(blockhist, offsets, partials, T);
    scan_add2_kernel<<<SB, THREADS, 0, stream>>>(offsets, partials, T, SB);

    bin_write_kernel<<<NBLK, BIGT, 0, stream>>>(ei, flag, offsets, ebuf, E, NB);
    place_dense_kernel<<<NB, BIGT, 0, stream>>>(ebuf, offsets, x, W1, rowptr, dinv, col, ht1, N, NB);

    int GB = (N * 32 + THREADS - 1) / THREADS;
    agg_dense_kernel<<<GB, THREADS, 0, stream>>>(ht1, rowptr, col, dinv, b1, W2, ht2, N);
    agg_final_kernel<<<GB, THREADS, 0, stream>>>(ht2, rowptr, col, dinv, b2, out, N);
}

// Round 13
// 274.742 us; speedup vs baseline: 1.1377x; 1.0597x over previous
//
#include <hip/hip_runtime.h>

#define THREADS 256
#define BIGT 1024             // wide blocks for latency-bound passes
#define NBLK 256              // blocks for bin passes (private-region radix)
#define BSHIFT 8              // 256 dst-nodes per bucket
#define BSZ (1 << BSHIFT)
#define MAXB 512              // max buckets (N <= 131072)

// ---------- edge_index dtype probe: int64 high-words (values in [0,2^31)) are all 0 ----------
__global__ void detect_kernel(const unsigned int* ei_words, int* flag_int64, long long n_words) {
    __shared__ int nonzero;
    if (threadIdx.x == 0) nonzero = 0;
    __syncthreads();
    long long w = 2LL * threadIdx.x + 1;   // odd word positions = int64 high words
    if (w < n_words) {
        if (ei_words[w] != 0u) atomicOr(&nonzero, 1);
    }
    __syncthreads();
    if (threadIdx.x == 0) *flag_int64 = (nonzero == 0) ? 1 : 0;
}

// ---------- pass 1: per-block bucket histogram over dst (reads raw edge_index) ----------
__global__ __launch_bounds__(BIGT) void bin_count_kernel(
        const void* __restrict__ ei, const int* __restrict__ flag_int64,
        int* __restrict__ blockhist, int E, int NB) {
    __shared__ int h[MAXB];
    int tid = threadIdx.x;
    for (int i = tid; i < NB; i += blockDim.x) h[i] = 0;
    __syncthreads();
    int chunk = (E + gridDim.x - 1) / gridDim.x;
    int s = blockIdx.x * chunk;
    int e = min(E, s + chunk);
    if (*flag_int64) {
        const long long* p = (const long long*)ei;
        for (int i = s + tid; i < e; i += blockDim.x)
            atomicAdd(&h[(int)p[E + i] >> BSHIFT], 1);
    } else {
        const int* p = (const int*)ei;
        for (int i = s + tid; i < e; i += blockDim.x)
            atomicAdd(&h[p[E + i] >> BSHIFT], 1);
    }
    __syncthreads();
    for (int i = tid; i < NB; i += blockDim.x)
        blockhist[i * NBLK + blockIdx.x] = h[i];   // bucket-major for scan
}

// ---------- pass 2: write edges into private (bucket, block) regions; no global atomics ----------
__global__ __launch_bounds__(BIGT) void bin_write_kernel(
        const void* __restrict__ ei, const int* __restrict__ flag_int64,
        const int* __restrict__ offsets, unsigned int* __restrict__ ebuf,
        int E, int NB) {
    __shared__ int cur[MAXB];
    int tid = threadIdx.x;
    for (int i = tid; i < NB; i += blockDim.x)
        cur[i] = offsets[i * NBLK + blockIdx.x];
    __syncthreads();
    int chunk = (E + gridDim.x - 1) / gridDim.x;
    int s = blockIdx.x * chunk;
    int e = min(E, s + chunk);
    if (*flag_int64) {
        const long long* p = (const long long*)ei;
        for (int i = s + tid; i < e; i += blockDim.x) {
            int d = (int)p[E + i];
            int sr = (int)p[i];
            int pos = atomicAdd(&cur[d >> BSHIFT], 1);   // LDS cursor -> private region
            ebuf[pos] = ((unsigned int)(d & (BSZ - 1)) << 20) | (unsigned int)sr;  // src < 2^20
        }
    } else {
        const int* p = (const int*)ei;
        for (int i = s + tid; i < e; i += blockDim.x) {
            int d = p[E + i];
            int sr = p[i];
            int pos = atomicAdd(&cur[d >> BSHIFT], 1);
            ebuf[pos] = ((unsigned int)(d & (BSZ - 1)) << 20) | (unsigned int)sr;
        }
    }
}

// ---------- scan kernel 1: per-1024-chunk local exclusive scan + chunk totals ----------
__global__ void scan_blocks_kernel(const int* __restrict__ cnt, int* __restrict__ ofs,
                                   int* __restrict__ partials, int T) {
    __shared__ int sd[THREADS];
    int tid = threadIdx.x;
    int base = blockIdx.x * 1024 + tid * 4;
    int c0 = (base + 0 < T) ? cnt[base + 0] : 0;
    int c1 = (base + 1 < T) ? cnt[base + 1] : 0;
    int c2 = (base + 2 < T) ? cnt[base + 2] : 0;
    int c3 = (base + 3 < T) ? cnt[base + 3] : 0;
    int tsum = c0 + c1 + c2 + c3;
    sd[tid] = tsum;
    __syncthreads();
    for (int off = 1; off < THREADS; off <<= 1) {
        int t = (tid >= off) ? sd[tid - off] : 0;
        __syncthreads();
        sd[tid] += t;
        __syncthreads();
    }
    int excl = sd[tid] - tsum;
    if (base + 0 < T) ofs[base + 0] = excl;
    if (base + 1 < T) ofs[base + 1] = excl + c0;
    if (base + 2 < T) ofs[base + 2] = excl + c0 + c1;
    if (base + 3 < T) ofs[base + 3] = excl + c0 + c1 + c2;
    if (tid == THREADS - 1) partials[blockIdx.x] = sd[tid];
}

// ---------- scan kernel 2: each block re-scans partials in LDS, adds its prefix ----------
__global__ void scan_add2_kernel(int* __restrict__ ofs, const int* __restrict__ partials,
                                 int T, int SB) {
    __shared__ int sd[128];
    int tid = threadIdx.x;
    if (tid < 128) sd[tid] = (tid < SB) ? partials[tid] : 0;
    __syncthreads();
    for (int off = 1; off < 128; off <<= 1) {
        int t = (tid < 128 && tid >= off) ? sd[tid - off] : 0;
        __syncthreads();
        if (tid < 128) sd[tid] += t;
        __syncthreads();
    }
    int add = (blockIdx.x > 0) ? sd[blockIdx.x - 1] : 0;   // exclusive prefix of this chunk
    int base = blockIdx.x * 1024 + tid * 4;
    if (base + 0 < T) ofs[base + 0] += add;
    if (base + 1 < T) ofs[base + 1] += add;
    if (base + 2 < T) ofs[base + 2] += add;
    if (base + 3 < T) ofs[base + 3] += add;
    if (blockIdx.x == gridDim.x - 1 && tid == 0) ofs[T] = sd[SB - 1];   // grand total = E
}

// ---------- fused per-bucket: degree/rowptr/dinv + col placement + dense1 ----------
// one 1024-thread block per 256-node bucket (Wt in LDS: keeps VGPR low for other loops)
__global__ __launch_bounds__(BIGT) void place_dense_kernel(
        const unsigned int* __restrict__ ebuf, const int* __restrict__ offsets,
        const float* __restrict__ x, const float* __restrict__ W1,
        int* __restrict__ rowptr, float* __restrict__ dinv, int* __restrict__ col,
        float* __restrict__ ht1, int N, int NB) {
    __shared__ int cnt[BSZ];
    __shared__ int scanbuf[BSZ];
    __shared__ int baseL[BSZ];
    __shared__ int fillL[BSZ];
    __shared__ float dinvL[BSZ];
    __shared__ float Wt[1024];    // Wt[k*32+j] = W1[j*32+k]
    __shared__ float xs[BIGT];
    int b = blockIdx.x;
    int lo = b << BSHIFT;
    int tid = threadIdx.x;
    if (tid < BSZ) cnt[tid] = 0;
    Wt[(tid & 31) * 32 + (tid >> 5)] = W1[tid];   // BIGT == 1024 covers all
    __syncthreads();
    int start = offsets[b * NBLK];
    int end   = offsets[(b + 1) * NBLK];   // b = NB-1 reads offsets[T] = E
    // pass A: per-node degree count (ebuf region ~32KB, L2-resident)
    for (int p = start + tid; p < end; p += BIGT)
        atomicAdd(&cnt[(ebuf[p] >> 20) & (BSZ - 1)], 1);
    __syncthreads();
    // exclusive scan of cnt (only tid<BSZ touch LDS)
    int c = (tid < BSZ) ? cnt[tid] : 0;
    if (tid < BSZ) scanbuf[tid] = c;
    __syncthreads();
    for (int off = 1; off < BSZ; off <<= 1) {
        int t = (tid < BSZ && tid >= off) ? scanbuf[tid - off] : 0;
        __syncthreads();
        if (tid < BSZ) scanbuf[tid] += t;
        __syncthreads();
    }
    if (tid < BSZ) {
        int excl = scanbuf[tid] - c;
        int node = lo + tid;
        float dv = 1.0f / sqrtf((float)(c + 1));   // +1 self loop
        dinvL[tid] = dv;
        if (node < N) {
            rowptr[node] = start + excl;
            dinv[node] = dv;
            if (node == N - 1) rowptr[N] = start + excl + c;   // == E
        }
        baseL[tid] = start + excl;
        fillL[tid] = 0;
    }
    __syncthreads();
    // pass B: place (col writes confined to this bucket's ~50KB window; ebuf re-read is L2-hit)
    for (int p = start + tid; p < end; p += BIGT) {
        unsigned int v = ebuf[p];
        int dl = (v >> 20) & (BSZ - 1);
        int pos = baseL[dl] + atomicAdd(&fillL[dl], 1);
        col[pos] = (int)(v & 0xFFFFFu);
    }
    __syncthreads();
    // dense1: ht1[n] = (x[n] @ W1^T) * dinv[n]  for this bucket's 256 nodes
    for (int base0 = 0; base0 < BSZ * 32; base0 += BIGT) {
        int idx = base0 + tid;            // 0..8191
        int ln = idx >> 5;                // local node
        int node = lo + ln;
        xs[tid] = (node < N) ? x[(size_t)lo * 32 + idx] : 0.f;
        __syncthreads();
        if (node < N) {
            int j = idx & 31;
            const float* xr = xs + ((tid >> 5) << 5);
            float s = 0.f;
#pragma unroll
            for (int k = 0; k < 32; ++k) s = fmaf(xr[k], Wt[k * 32 + j], s);
            ht1[(size_t)node * 32 + j] = s * dinvL[ln];
        }
        __syncthreads();
    }
}

// ---------- fused agg1 + dense2: ht2 = ((relu(dinv*(gather)+b1)) @ W2^T) * dinv ----------
// R9 form exactly: plain col loads (L2-cached stream), Wt in LDS (VGPR~20 -> full MLP)
__global__ __launch_bounds__(THREADS) void agg_dense_kernel(
        const float* __restrict__ ht1, const int* __restrict__ rowptr,
        const int* __restrict__ col, const float* __restrict__ dinv,
        const float* __restrict__ b1, const float* __restrict__ W2,
        float* __restrict__ ht2, int N) {
    __shared__ float Wt[1024];    // Wt[k*32+j] = W2[j*32+k]
    __shared__ float hr[THREADS]; // 8 node-rows of h1
    int tid = threadIdx.x;
    for (int idx = tid; idx < 1024; idx += THREADS)
        Wt[(idx & 31) * 32 + (idx >> 5)] = W2[idx];
    int gid = blockIdx.x * THREADS + tid;
    int n = gid >> 5;
    int j = gid & 31;
    bool act = (n < N);
    float h1v = 0.f, dv = 0.f;
    if (act) {
        dv = dinv[n];
        float s = ht1[gid];               // self loop
        int p = rowptr[n], end = rowptr[n + 1];
        for (; p + 8 <= end; p += 8) {
            int c0 = col[p], c1 = col[p + 1], c2 = col[p + 2], c3 = col[p + 3];
            int c4 = col[p + 4], c5 = col[p + 5], c6 = col[p + 6], c7 = col[p + 7];
            float v0 = ht1[c0 * 32 + j];
            float v1 = ht1[c1 * 32 + j];
            float v2 = ht1[c2 * 32 + j];
            float v3 = ht1[c3 * 32 + j];
            float v4 = ht1[c4 * 32 + j];
            float v5 = ht1[c5 * 32 + j];
            float v6 = ht1[c6 * 32 + j];
            float v7 = ht1[c7 * 32 + j];
            s += ((v0 + v1) + (v2 + v3)) + ((v4 + v5) + (v6 + v7));
        }
        for (; p + 4 <= end; p += 4) {
            int c0 = col[p], c1 = col[p + 1], c2 = col[p + 2], c3 = col[p + 3];
            float v0 = ht1[c0 * 32 + j];
            float v1 = ht1[c1 * 32 + j];
            float v2 = ht1[c2 * 32 + j];
            float v3 = ht1[c3 * 32 + j];
            s += (v0 + v1) + (v2 + v3);
        }
        for (; p < end; ++p) s += ht1[col[p] * 32 + j];
        h1v = fmaxf(fmaf(dv, s, b1[j]), 0.f);
    }
    hr[tid] = h1v;
    __syncthreads();                       // also covers Wt load
    if (act) {
        const float* hrow = hr + ((tid >> 5) << 5);
        float t = 0.f;
#pragma unroll
        for (int k = 0; k < 32; ++k) t = fmaf(hrow[k], Wt[k * 32 + j], t);
        ht2[gid] = t * dv;
    }
}

// ---------- final aggregate: out = relu(dinv * (self + gather) + b2) ----------
__global__ __launch_bounds__(THREADS) void agg_final_kernel(
        const float* __restrict__ ht2, const int* __restrict__ rowptr,
        const int* __restrict__ col, const float* __restrict__ dinv,
        const float* __restrict__ bias, float* __restrict__ out, int N) {
    int gid = blockIdx.x * THREADS + threadIdx.x;
    int n = gid >> 5;
    if (n >= N) return;
    int j = gid & 31;
    float s = ht2[gid];
    int p = rowptr[n], end = rowptr[n + 1];
    for (; p + 8 <= end; p += 8) {
        int c0 = col[p], c1 = col[p + 1], c2 = col[p + 2], c3 = col[p + 3];
        int c4 = col[p + 4], c5 = col[p + 5], c6 = col[p + 6], c7 = col[p + 7];
        float v0 = ht2[c0 * 32 + j];
        float v1 = ht2[c1 * 32 + j];
        float v2 = ht2[c2 * 32 + j];
        float v3 = ht2[c3 * 32 + j];
        float v4 = ht2[c4 * 32 + j];
        float v5 = ht2[c5 * 32 + j];
        float v6 = ht2[c6 * 32 + j];
        float v7 = ht2[c7 * 32 + j];
        s += ((v0 + v1) + (v2 + v3)) + ((v4 + v5) + (v6 + v7));
    }
    for (; p + 4 <= end; p += 4) {
        int c0 = col[p], c1 = col[p + 1], c2 = col[p + 2], c3 = col[p + 3];
        float v0 = ht2[c0 * 32 + j];
        float v1 = ht2[c1 * 32 + j];
        float v2 = ht2[c2 * 32 + j];
        float v3 = ht2[c3 * 32 + j];
        s += (v0 + v1) + (v2 + v3);
    }
    for (; p < end; ++p) s += ht2[col[p] * 32 + j];
    float r = fmaxf(fmaf(dinv[n], s, bias[j]), 0.f);
    __builtin_nontemporal_store(r, out + gid);   // output never re-read
}

extern "C" void kernel_launch(void* const* d_in, const int* in_sizes, int n_in,
                              void* d_out, int out_size, void* d_ws, size_t ws_size,
                              hipStream_t stream) {
    const float* x  = (const float*)d_in[0];
    const void*  ei = d_in[1];
    const float* W1 = (const float*)d_in[2];
    const float* b1 = (const float*)d_in[3];
    const float* W2 = (const float*)d_in[4];
    const float* b2 = (const float*)d_in[5];
    float* out = (float*)d_out;

    int N = in_sizes[0] / 32;
    long long twoE = (long long)in_sizes[1];
    int E = (int)(twoE / 2);
    int NB = (N + BSZ - 1) >> BSHIFT;          // buckets (391 for N=100000)
    int T  = NB * NBLK;                        // blockhist entries (100096)

    char* ws = (char*)d_ws;
    size_t o = 0;
    auto alloc = [&](size_t bytes) { size_t r = o; o += (bytes + 255) & ~(size_t)255; return r; };
    int*   flag      = (int*)(ws + alloc(4));
    int*   blockhist = (int*)(ws + alloc((size_t)T * 4));
    int*   offsets   = (int*)(ws + alloc((size_t)(T + 1) * 4));
    int*   rowptr    = (int*)(ws + alloc((size_t)(N + 1) * 4));
    int*   partials  = (int*)(ws + alloc(512));
    float* dinv      = (float*)(ws + alloc((size_t)N * 4));
    unsigned int* ebuf = (unsigned int*)(ws + alloc((size_t)E * 4));
    int*   col       = (int*)(ws + alloc((size_t)E * 4));
    float* ht1       = (float*)(ws + alloc((size_t)N * 32 * 4));
    float* ht2       = (float*)(ws + alloc((size_t)N * 32 * 4));

    detect_kernel<<<1, 256, 0, stream>>>((const unsigned int*)ei, flag, twoE);

    bin_count_kernel<<<NBLK, BIGT, 0, stream>>>(ei, flag, blockhist, E, NB);

    int SB = (T + 1023) / 1024;   // 98 (<=128)
    scan_blocks_kernel<<<SB, THREADS, 0, stream>>>(blockhist, offsets, partials, T);
    scan_add2_kernel<<<SB, THREADS, 0, stream>>>(offsets, partials, T, SB);

    bin_write_kernel<<<NBLK, BIGT, 0, stream>>>(ei, flag, offsets, ebuf, E, NB);
    place_dense_kernel<<<NB, BIGT, 0, stream>>>(ebuf, offsets, x, W1, rowptr, dinv, col, ht1, N, NB);

    int GB = (N * 32 + THREADS - 1) / THREADS;
    agg_dense_kernel<<<GB, THREADS, 0, stream>>>(ht1, rowptr, col, dinv, b1, W2, ht2, N);
    agg_final_kernel<<<GB, THREADS, 0, stream>>>(ht2, rowptr, col, dinv, b2, out, N);
}